// Round 9
// baseline (546.526 us; speedup 1.0000x reference)
//
#include <hip/hip_runtime.h>
#include <math.h>

namespace {

constexpr int Sq = 43;
constexpr int Dm = 18;
constexpr int Dff = 2048;
constexpr int Am = 128;
constexpr int Nb = 7;
constexpr int NR = 11008;          // B*SEQ rows
constexpr int RSZ = NR * Dm;       // 198144 floats
constexpr float EPSf = 1e-6f;

// MFMA fragment types (per cdna_hip_programming.md §3, gfx950)
typedef __attribute__((ext_vector_type(8))) short bf16x8;
typedef __attribute__((ext_vector_type(4))) float f32x4;

__device__ __forceinline__ bf16x8 FRAG(uint4 u) {
    return __builtin_bit_cast(bf16x8, u);
}

// ---------------------------------------------------------------------------
// k_attn: fused per-layer front half (R7 main path, UNCHANGED).
//   blocks 0..255  : batch b; 192 thr = 3 waves; wave h owns head h.
//   layer-0 extras : 256..319 MFMA weight-fragment prep; 320 tail precompute.
//
// Fragment prep packs W1^T and W2^T as bf16 hi/lo MFMA A-fragments:
//  W1F[(l*64+c)*256 + t*128 + s*64 + lane] (uint4):
//    lane: m=lane&15, g=lane>>4; j = c*32 + t*16 + m; elems i=0..7: k = 8g+i;
//    value = (k<18) ? W1[l][k][j] : 0;  s=0: hi-trunc, s=1: (v-hi)-trunc.
//  W2F same indexing: j = c*32 + 8g + i;  t=0: d = m;  t=1: d = 16+m (m<2).
// ---------------------------------------------------------------------------
__global__ __launch_bounds__(192) void k_attn(
    int layer,
    const float* __restrict__ Xi, float* __restrict__ Xn,
    float* __restrict__ x2g,
    const int* __restrict__ maskg,
    const float* __restrict__ Wq, const float* __restrict__ bq,
    const float* __restrict__ Wk, const float* __restrict__ bk,
    const float* __restrict__ Wv, const float* __restrict__ bv,
    const float* __restrict__ ln1a, const float* __restrict__ ln1b,
    const float* __restrict__ Wo, const float* __restrict__ bo,
    const float* __restrict__ ln2a, const float* __restrict__ ln2b,
    const float* __restrict__ b2g,
    const float* __restrict__ fW1g, const float* __restrict__ fW2g,
    uint4* __restrict__ W1F, uint4* __restrict__ W2F,
    const float* __restrict__ llW, const float* __restrict__ llb,
    const float* __restrict__ flW, const float* __restrict__ flb,
    const float* __restrict__ ll2b,
    float* __restrict__ Mw, float* __restrict__ PS1, float* __restrict__ QS2)
{
    __shared__ __align__(16) float ks[Sq * 20];
    __shared__ __align__(16) float vs[Sq * 20];
    __shared__ float os[Sq * Dm];
    __shared__ int ms[Sq];
    __shared__ float M[602];
    __shared__ float cc2[14];
    __shared__ float SS[14];

    const int tid = threadIdx.x;
    const int b = blockIdx.x;

    if (b >= 256) {                       // layer-0 auxiliary blocks only
        if (b < 320) {
            // ---- MFMA weight-fragment prep: 12288 threads, 98304 entries ----
            for (int e = (b - 256) * 192 + tid; e < 98304; e += 12288) {
                const int lane = e & 63;
                const int s = (e >> 6) & 1;
                const int t = (e >> 7) & 1;
                const int c = (e >> 8) & 63;
                const int l = e >> 14;
                const int g = lane >> 4, m = lane & 15;
                // W1F
                {
                    const int j = c * 32 + t * 16 + m;
                    unsigned u[4] = {0u, 0u, 0u, 0u};
                    #pragma unroll
                    for (int i = 0; i < 8; i++) {
                        const int k = 8 * g + i;
                        float v = (k < 18)
                            ? fW1g[((size_t)l * Dm + k) * Dff + j] : 0.f;
                        unsigned hb = __float_as_uint(v) & 0xFFFF0000u;
                        unsigned bits;
                        if (s == 0) bits = hb >> 16;
                        else {
                            float lo = v - __uint_as_float(hb);
                            bits = (__float_as_uint(lo) & 0xFFFF0000u) >> 16;
                        }
                        u[i >> 1] |= bits << (16 * (i & 1));
                    }
                    W1F[e] = make_uint4(u[0], u[1], u[2], u[3]);
                }
                // W2F
                {
                    unsigned u[4] = {0u, 0u, 0u, 0u};
                    const int d = (t == 0) ? m : 16 + m;
                    const bool valid = (t == 0) || (m < 2);
                    #pragma unroll
                    for (int i = 0; i < 8; i++) {
                        const int j = c * 32 + 8 * g + i;
                        float v = valid
                            ? fW2g[((size_t)l * Dff + j) * Dm + d] : 0.f;
                        unsigned hb = __float_as_uint(v) & 0xFFFF0000u;
                        unsigned bits;
                        if (s == 0) bits = hb >> 16;
                        else {
                            float lo = v - __uint_as_float(hb);
                            bits = (__float_as_uint(lo) & 0xFFFF0000u) >> 16;
                        }
                        u[i >> 1] |= bits << (16 * (i & 1));
                    }
                    W2F[e] = make_uint4(u[0], u[1], u[2], u[3]);
                }
            }
            return;
        }
        // ---- b == 320: tail precompute (Mw / PS1 / QS2) ----
        for (int m = tid; m < 602; m += 192) {
            int half = m / 301, rem = m - half * 301;
            int s = rem / 7, n = rem - 7 * s;
            float a = 0.f;
            for (int jj = 0; jj < Am; jj++)
                a += llW[s * Am + jj] * flW[(half * Am + jj) * Nb + n];
            M[m] = a;
        }
        if (tid < 14) {
            int half = tid / 7, n = tid - 7 * (tid / 7);
            float a = 0.f;
            for (int jj = 0; jj < Am; jj++)
                a += llb[jj] * flW[(half * Am + jj) * Nb + n];
            cc2[tid] = a;
        }
        __syncthreads();
        if (tid < 14) {
            int half = tid / 7, n = tid - 7 * (tid / 7);
            float s2 = 0.f;
            for (int s = 0; s < Sq; s++) s2 += M[half * 301 + s * 7 + n];
            SS[tid] = s2;
        }
        __syncthreads();
        for (int m = tid; m < 602; m += 192) Mw[m] = M[m];
        for (int m = tid; m < 896; m += 192) {
            int i = m / 7, n = m - 7 * i;
            PS1[m] = cc2[n] + ll2b[i] * SS[n];
            QS2[m] = cc2[7 + n] + ll2b[i] * SS[7 + n] + flb[n];
        }
        return;
    }

    // -------------------- main path: one batch per block --------------------
    const float scale = 0.40824829046386296f;  // 1/sqrt(6)
    const int h = tid >> 6;        // wave id = head 0..2
    const int q = tid & 63;        // lane = query row

    if (tid < Sq) ms[tid] = maskg[b * Sq + tid];

    float y[Dm];
    float qv6[6];
    if (q < Sq) {
        const size_t ro = (size_t)(b * Sq + q) * Dm;
        #pragma unroll
        for (int k = 0; k < 9; k++) {
            float2 t = *(const float2*)(Xi + ro + 2 * k);
            y[2 * k] = t.x; y[2 * k + 1] = t.y;
        }
        // LN1 (computed by all 3 waves redundantly -> identical bits)
        float mu = 0.f;
        #pragma unroll
        for (int d = 0; d < Dm; d++) mu += y[d];
        mu *= (1.f / Dm);
        float var = 0.f;
        #pragma unroll
        for (int d = 0; d < Dm; d++) { float t = y[d] - mu; var += t * t; }
        var *= (1.f / (Dm - 1));                 // ddof=1
        float isd = 1.f / (sqrtf(var) + EPSf);   // eps on sd
        float x2[Dm];
        #pragma unroll
        for (int d = 0; d < Dm; d++)
            x2[d] = ln1a[layer * Dm + d] * (y[d] - mu) * isd
                  + ln1b[layer * Dm + d];
        // q/k/v: ONLY this wave's head slice (d = h*6+dh), same chains
        const float* wqp = Wq + layer * Dm * Dm;
        const float* wkp = Wk + layer * Dm * Dm;
        const float* wvp = Wv + layer * Dm * Dm;
        #pragma unroll
        for (int dh = 0; dh < 6; dh++) {
            const int d = h * 6 + dh;
            float aq = bq[layer * Dm + d];
            float ak = bk[layer * Dm + d];
            float av = bv[layer * Dm + d];
            #pragma unroll
            for (int dd = 0; dd < Dm; dd++) {
                aq += x2[dd] * wqp[dd * Dm + d];
                ak += x2[dd] * wkp[dd * Dm + d];
                av += x2[dd] * wvp[dd * Dm + d];
            }
            qv6[dh] = aq;
            ks[q * 20 + d] = ak;
            vs[q * 20 + d] = av;
        }
    }
    __syncthreads();

    // phase 2: this wave's head attention (identical chain & j-order)
    if (q < Sq) {
        float sum = 0.f;
        float o6[6];
        #pragma unroll
        for (int d = 0; d < 6; d++) o6[d] = 0.f;
        const float q0 = qv6[0], q1 = qv6[1], q2 = qv6[2];
        const float q3 = qv6[3], q4 = qv6[4], q5 = qv6[5];
        for (int j = 0; j < Sq; j++) {
            const float* kr = ks + j * 20 + h * 6;   // 8B-aligned (h*6 even)
            const float2 k0 = *(const float2*)(kr);
            const float2 k1 = *(const float2*)(kr + 2);
            const float2 k2 = *(const float2*)(kr + 4);
            float t = q0 * k0.x + q1 * k0.y + q2 * k1.x +
                      q3 * k1.y + q4 * k2.x + q5 * k2.y;
            t *= scale;
            if (ms[j] == 0) t = -1e9f;
            float e = __expf(t);
            sum += e;
            const float* vr = vs + j * 20 + h * 6;
            const float2 v0 = *(const float2*)(vr);
            const float2 v1 = *(const float2*)(vr + 2);
            const float2 v2 = *(const float2*)(vr + 4);
            o6[0] += e * v0.x; o6[1] += e * v0.y; o6[2] += e * v1.x;
            o6[3] += e * v1.y; o6[4] += e * v2.x; o6[5] += e * v2.y;
        }
        float inv = 1.f / sum;
        #pragma unroll
        for (int d = 0; d < 6; d++) os[q * Dm + h * 6 + d] = o6[d] * inv;
    }
    __syncthreads();

    // phase 3: wave 0 -> o-proj + residual + next-x seed + LN2 (same chains)
    if (h == 0 && q < Sq) {
        const float* wo = Wo + layer * Dm * Dm;
        const float* orow = os + q * Dm;
        float yo[Dm];
        #pragma unroll 3
        for (int d = 0; d < Dm; d++) {
            float t = bo[layer * Dm + d];
            #pragma unroll
            for (int dd = 0; dd < Dm; dd++) t += orow[dd] * wo[dd * Dm + d];
            yo[d] = y[d] + t;
        }
        const size_t ro = (size_t)(b * Sq + q) * Dm;
        #pragma unroll
        for (int d = 0; d < Dm; d++)
            Xn[ro + d] = yo[d] + b2g[layer * Dm + d];  // seed: FFN atomics add
        float mu = 0.f;
        #pragma unroll
        for (int d = 0; d < Dm; d++) mu += yo[d];
        mu *= (1.f / Dm);
        float var = 0.f;
        #pragma unroll
        for (int d = 0; d < Dm; d++) { float t = yo[d] - mu; var += t * t; }
        var *= (1.f / (Dm - 1));
        float isd = 1.f / (sqrtf(var) + EPSf);
        #pragma unroll
        for (int d = 0; d < Dm; d++)
            x2g[ro + d] =
                ln2a[layer * Dm + d] * (yo[d] - mu) * isd + ln2b[layer * Dm + d];
    }
}

// ---------------------------------------------------------------------------
// k_ffn (R9): MFMA split-bf16, v2. Fixes R8's two structural flaws:
//  (a) 32-row blocks (344 blocks, 2 row-tiles): the 8 weight fragments per
//      chunk load ONCE and feed 24 MFMA (2 row-tiles) instead of 12 ->
//      2x arithmetic intensity, weight L2 traffic 352 -> 176 MB/launch.
//  (b) register double-buffered weight prefetch (the proven R4 pattern):
//      chunk c+1's 8 uint4 issue before chunk c's MFMAs; clamped at the
//      last iteration (no OOB).
// Per-row arithmetic identical to R8 (same fragments, same mfma order,
// same c-ascending accumulation, same atomics) -> absmax unchanged.
// No __syncthreads (per-wave LDS regions; wave-internal lgkmcnt ordering).
// ---------------------------------------------------------------------------
__global__ __launch_bounds__(256) void k_ffn(
    int layer, const float* __restrict__ x2g,
    const uint4* __restrict__ W1F, const uint4* __restrict__ W2F,
    const float* __restrict__ fb1g, float* __restrict__ Xn)
{
    // per-wave, per-row-tile H buffers: [wave][rt][hi/lo][16 rows x 40 shorts]
    __shared__ __align__(16) short Hbuf[4][2][2][640];

    const int tid  = threadIdx.x;
    const int lane = tid & 63;
    const int wv   = tid >> 6;
    const int g    = lane >> 4;
    const int m    = lane & 15;
    const int rbase = blockIdx.x * 32;

    // ---- build X^T B-fragments (hi/lo) for both row-tiles ----
    bf16x8 Bxhi[2], Bxlo[2];
    #pragma unroll
    for (int rt = 0; rt < 2; ++rt) {
        const int row = rbase + rt * 16 + m;
        unsigned bh[4] = {0u, 0u, 0u, 0u}, bl[4] = {0u, 0u, 0u, 0u};
        #pragma unroll
        for (int i = 0; i < 8; i++) {
            const int k = 8 * g + i;
            float v = (k < 18) ? x2g[(size_t)row * Dm + k] : 0.f;
            unsigned hbits = __float_as_uint(v) & 0xFFFF0000u;
            float lo = v - __uint_as_float(hbits);
            unsigned lbits = __float_as_uint(lo) & 0xFFFF0000u;
            bh[i >> 1] |= (hbits >> 16) << (16 * (i & 1));
            bl[i >> 1] |= (lbits >> 16) << (16 * (i & 1));
        }
        Bxhi[rt] = FRAG(make_uint4(bh[0], bh[1], bh[2], bh[3]));
        Bxlo[rt] = FRAG(make_uint4(bl[0], bl[1], bl[2], bl[3]));
    }

    f32x4 y0[2], y1[2];
    #pragma unroll
    for (int rt = 0; rt < 2; ++rt) {
        y0[rt] = (f32x4){0.f, 0.f, 0.f, 0.f};
        y1[rt] = (f32x4){0.f, 0.f, 0.f, 0.f};
    }
    const uint4* w1b = W1F + (size_t)layer * 16384;
    const uint4* w2b = W2F + (size_t)layer * 16384;
    const float* b1b = fb1g + layer * Dff;

    const int c0 = wv * 16;
    // prefetch chunk c0 weights (8 x uint4, wave-uniform-per-lane-group addrs)
    uint4 A0 = w1b[c0 * 256 + lane],        A1 = w1b[c0 * 256 + 64 + lane];
    uint4 A2 = w1b[c0 * 256 + 128 + lane],  A3 = w1b[c0 * 256 + 192 + lane];
    uint4 C0 = w2b[c0 * 256 + lane],        C1 = w2b[c0 * 256 + 64 + lane];
    uint4 C2 = w2b[c0 * 256 + 128 + lane],  C3 = w2b[c0 * 256 + 192 + lane];

    for (int c = c0; c < c0 + 16; ++c) {
        const int cn = (c + 1 < c0 + 16) ? c + 1 : c;   // clamped (no OOB)
        const uint4 nA0 = w1b[cn * 256 + lane],       nA1 = w1b[cn * 256 + 64 + lane];
        const uint4 nA2 = w1b[cn * 256 + 128 + lane], nA3 = w1b[cn * 256 + 192 + lane];
        const uint4 nC0 = w2b[cn * 256 + lane],       nC1 = w2b[cn * 256 + 64 + lane];
        const uint4 nC2 = w2b[cn * 256 + 128 + lane], nC3 = w2b[cn * 256 + 192 + lane];

        const f32x4 bb0 = *(const f32x4*)(b1b + c * 32 + 4 * g);
        const f32x4 bb1 = *(const f32x4*)(b1b + c * 32 + 16 + 4 * g);

        #pragma unroll
        for (int rt = 0; rt < 2; ++rt) {
            short* Hh = &Hbuf[wv][rt][0][0];
            short* Hl = &Hbuf[wv][rt][1][0];
            // ---- GEMM1: two 16-j tiles -> H chunk in LDS ----
            #pragma unroll
            for (int t = 0; t < 2; ++t) {
                const uint4 ah = (t == 0) ? A0 : A2;
                const uint4 al = (t == 0) ? A1 : A3;
                const f32x4 bb = (t == 0) ? bb0 : bb1;
                f32x4 c1 = {0.f, 0.f, 0.f, 0.f};
                c1 = __builtin_amdgcn_mfma_f32_16x16x32_bf16(FRAG(ah), Bxhi[rt], c1, 0, 0, 0);
                c1 = __builtin_amdgcn_mfma_f32_16x16x32_bf16(FRAG(al), Bxhi[rt], c1, 0, 0, 0);
                c1 = __builtin_amdgcn_mfma_f32_16x16x32_bf16(FRAG(ah), Bxlo[rt], c1, 0, 0, 0);
                unsigned ph[2], pl[2];
                #pragma unroll
                for (int r2 = 0; r2 < 2; ++r2) {
                    float h0 = fmaxf(c1[2 * r2] + bb[2 * r2], 0.f);
                    float h1 = fmaxf(c1[2 * r2 + 1] + bb[2 * r2 + 1], 0.f);
                    unsigned h0b = __float_as_uint(h0) & 0xFFFF0000u;
                    unsigned h1b = __float_as_uint(h1) & 0xFFFF0000u;
                    ph[r2] = (h0b >> 16) | h1b;
                    float l0 = h0 - __uint_as_float(h0b);
                    float l1 = h1 - __uint_as_float(h1b);
                    pl[r2] = ((__float_as_uint(l0) & 0xFFFF0000u) >> 16)
                           | (__float_as_uint(l1) & 0xFFFF0000u);
                }
                const int joff = m * 40 + t * 16 + 4 * g;   // shorts
                *(uint2*)&Hh[joff] = make_uint2(ph[0], ph[1]);
                *(uint2*)&Hl[joff] = make_uint2(pl[0], pl[1]);
            }
            // ---- GEMM2: consume H chunk, accumulate Y^T ----
            const bf16x8 bH = FRAG(*(const uint4*)&Hh[m * 40 + 8 * g]);
            const bf16x8 bL = FRAG(*(const uint4*)&Hl[m * 40 + 8 * g]);
            y0[rt] = __builtin_amdgcn_mfma_f32_16x16x32_bf16(FRAG(C0), bH, y0[rt], 0, 0, 0);
            y0[rt] = __builtin_amdgcn_mfma_f32_16x16x32_bf16(FRAG(C1), bH, y0[rt], 0, 0, 0);
            y0[rt] = __builtin_amdgcn_mfma_f32_16x16x32_bf16(FRAG(C0), bL, y0[rt], 0, 0, 0);
            y1[rt] = __builtin_amdgcn_mfma_f32_16x16x32_bf16(FRAG(C2), bH, y1[rt], 0, 0, 0);
            y1[rt] = __builtin_amdgcn_mfma_f32_16x16x32_bf16(FRAG(C3), bH, y1[rt], 0, 0, 0);
            y1[rt] = __builtin_amdgcn_mfma_f32_16x16x32_bf16(FRAG(C2), bL, y1[rt], 0, 0, 0);
        }

        A0 = nA0; A1 = nA1; A2 = nA2; A3 = nA3;
        C0 = nC0; C1 = nC1; C2 = nC2; C3 = nC3;
    }

    // ---- accumulate into Xn (device-scope f32 atomics, as since R3) ----
    #pragma unroll
    for (int rt = 0; rt < 2; ++rt) {
        const int row = rbase + rt * 16 + m;
        #pragma unroll
        for (int r = 0; r < 4; ++r)
            unsafeAtomicAdd(&Xn[(size_t)row * Dm + 4 * g + r], y0[rt][r]);
        if (g == 0) {
            unsafeAtomicAdd(&Xn[(size_t)row * Dm + 16], y1[rt][0]);
            unsafeAtomicAdd(&Xn[(size_t)row * Dm + 17], y1[rt][1]);
        }
    }
}

// ---------------------------------------------------------------------------
// k_out: (i-chunk, batch) blocks; float4 stores of the 117 MB output.
// (UNCHANGED)
// ---------------------------------------------------------------------------
__global__ __launch_bounds__(256) void k_out(
    const float* __restrict__ xg,
    const float* __restrict__ ll2W,
    const float* __restrict__ Mw, const float* __restrict__ PS1,
    const float* __restrict__ QS2, float* __restrict__ out)
{
    __shared__ float xb[Sq * Dm];
    __shared__ float M[602];
    __shared__ float T[2][Dm][Nb];
    __shared__ float Pc[32 * Nb];
    __shared__ float QBs[Am * Nb];

    const int b = blockIdx.y, chunk = blockIdx.x, tid = threadIdx.x;

    for (int e = tid; e < Sq * Dm; e += 256)
        xb[e] = xg[(size_t)b * (Sq * Dm) + e];
    for (int m = tid; m < 602; m += 256) M[m] = Mw[m];
    __syncthreads();

    for (int m = tid; m < 252; m += 256) {
        int half = m / 126, rem = m - half * 126;
        int d = rem / 7, n = rem - 7 * d;
        float a = 0.f;
        for (int s = 0; s < Sq; s++)
            a += xb[s * Dm + d] * M[half * 301 + s * 7 + n];
        T[half][d][n] = a;
    }
    __syncthreads();

    for (int m = tid; m < 224; m += 256) {
        int il = m / 7, n = m - 7 * il;
        int i = chunk * 32 + il;
        float a = PS1[i * 7 + n];
        #pragma unroll
        for (int d = 0; d < Dm; d++) a += T[0][d][n] * ll2W[d * Am + i];
        Pc[m] = a;
    }
    for (int e = tid; e < 896; e += 256) {
        int jj = e / 7, n = e - 7 * jj;
        float a = QS2[e];
        #pragma unroll
        for (int d = 0; d < Dm; d++) a += T[1][d][n] * ll2W[d * Am + jj];
        QBs[e] = a;
    }
    __syncthreads();

    if (tid < 224) {
        const int e = 4 * tid;
        const float q0 = QBs[e], q1 = QBs[e + 1], q2 = QBs[e + 2], q3 = QBs[e + 3];
        const int n0 = e % 7, n1 = (e + 1) % 7, n2 = (e + 2) % 7, n3 = (e + 3) % 7;
        const size_t base = (size_t)b * (Am * Am * Nb)
                          + (size_t)chunk * 32 * 896 + e;
        for (int il = 0; il < 32; il++) {
            const float* pc = Pc + il * 7;
            float4 v;
            v.x = pc[n0] + q0; v.y = pc[n1] + q1;
            v.z = pc[n2] + q2; v.w = pc[n3] + q3;
            *(float4*)(out + base + (size_t)il * 896) = v;
        }
    }
}

} // namespace

// ---------------------------------------------------------------------------
extern "C" void kernel_launch(void* const* d_in, const int* in_sizes, int n_in,
                              void* d_out, int out_size, void* d_ws, size_t ws_size,
                              hipStream_t stream)
{
    (void)in_sizes; (void)n_in; (void)out_size; (void)ws_size;

    const float* src  = (const float*)d_in[0];
    const int*   mask = (const int*)  d_in[1];
    const float* Wq   = (const float*)d_in[3];
    const float* bq   = (const float*)d_in[4];
    const float* Wk   = (const float*)d_in[5];
    const float* bk   = (const float*)d_in[6];
    const float* Wv   = (const float*)d_in[7];
    const float* bv   = (const float*)d_in[8];
    const float* Wo   = (const float*)d_in[9];
    const float* bo   = (const float*)d_in[10];
    const float* ln1a = (const float*)d_in[11];
    const float* ln1b = (const float*)d_in[12];
    const float* ln2a = (const float*)d_in[13];
    const float* ln2b = (const float*)d_in[14];
    const float* fW1  = (const float*)d_in[15];
    const float* fb1  = (const float*)d_in[16];
    const float* fW2  = (const float*)d_in[17];
    const float* fb2  = (const float*)d_in[18];
    const float* ll2W = (const float*)d_in[19];
    const float* ll2b = (const float*)d_in[20];
    const float* llW  = (const float*)d_in[21];
    const float* llb  = (const float*)d_in[22];
    const float* flW  = (const float*)d_in[23];
    const float* flb  = (const float*)d_in[24];
    float* out = (float*)d_out;

    float* ws  = (float*)d_ws;
    float* xA  = ws;
    float* xB  = ws + 1 * (size_t)RSZ;
    float* x2g = ws + 2 * (size_t)RSZ;
    uint4* W1F = (uint4*)(ws + 3 * (size_t)RSZ);      // 98304 uint4 (16B-aligned)
    uint4* W2F = W1F + 98304;
    float* Mw  = (float*)(W2F + 98304);               // 602 (pad 604)
    float* PS1 = Mw + 604;
    float* QS2 = PS1 + 896;                           // total ~5.5 MB

    for (int i = 0; i < 6; i++) {
        const float* Xi = (i == 0) ? src : ((i % 2 == 1) ? xB : xA);
        float*       Xn = (i % 2 == 0) ? xB : xA;
        const int nblk = (i == 0) ? 321 : 256;   // layer 0 carries prep blocks
        k_attn<<<nblk, 192, 0, stream>>>(i, Xi, Xn, x2g, mask,
                                         Wq, bq, Wk, bk, Wv, bv,
                                         ln1a, ln1b, Wo, bo, ln2a, ln2b, fb2,
                                         fW1, fW2, W1F, W2F,
                                         llW, llb, flW, flb, ll2b,
                                         Mw, PS1, QS2);
        k_ffn<<<344, 256, 0, stream>>>(i, x2g, W1F, W2F, fb1, Xn);
    }
    k_out<<<dim3(4, 256), 256, 0, stream>>>(xA, ll2W, Mw, PS1, QS2, out);
}

// Round 10
// 495.389 us; speedup vs baseline: 1.1032x; 1.1032x over previous
//
#include <hip/hip_runtime.h>
#include <math.h>

namespace {

constexpr int Sq = 43;
constexpr int Dm = 18;
constexpr int Dff = 2048;
constexpr int Am = 128;
constexpr int Nb = 7;
constexpr int NR = 11008;          // B*SEQ rows
constexpr int RSZ = NR * Dm;       // 198144 floats
constexpr int WROW = 20;           // padded weight row (18 w + b1 + pad)
constexpr float EPSf = 1e-6f;

typedef float v2f __attribute__((ext_vector_type(2)));
typedef float v4f __attribute__((ext_vector_type(4)));

// ---------------------------------------------------------------------------
// k_attn (R7, verbatim): head-parallel. 192 threads = 3 waves; wave h = head h.
//   blocks 0..255  : batch b.
//   layer-0 extras : 256..319 FFN weight prep (padded fp32 rows); 320 tail.
// ---------------------------------------------------------------------------
__global__ __launch_bounds__(192) void k_attn(
    int layer,
    const float* __restrict__ Xi, float* __restrict__ Xn,
    float* __restrict__ x2g,
    const int* __restrict__ maskg,
    const float* __restrict__ Wq, const float* __restrict__ bq,
    const float* __restrict__ Wk, const float* __restrict__ bk,
    const float* __restrict__ Wv, const float* __restrict__ bv,
    const float* __restrict__ ln1a, const float* __restrict__ ln1b,
    const float* __restrict__ Wo, const float* __restrict__ bo,
    const float* __restrict__ ln2a, const float* __restrict__ ln2b,
    const float* __restrict__ b2g,
    const float* __restrict__ fW1g, const float* __restrict__ fb1g,
    const float* __restrict__ fW2g,
    float* __restrict__ W1P, float* __restrict__ W2P,
    const float* __restrict__ llW, const float* __restrict__ llb,
    const float* __restrict__ flW, const float* __restrict__ flb,
    const float* __restrict__ ll2b,
    float* __restrict__ Mw, float* __restrict__ PS1, float* __restrict__ QS2)
{
    __shared__ __align__(16) float ks[Sq * 20];
    __shared__ __align__(16) float vs[Sq * 20];
    __shared__ float os[Sq * Dm];
    __shared__ int ms[Sq];
    __shared__ float M[602];
    __shared__ float cc2[14];
    __shared__ float SS[14];

    const int tid = threadIdx.x;
    const int b = blockIdx.x;

    if (b >= 256) {                       // layer-0 auxiliary blocks only
        if (b < 320) {
            // ---- FFN weight prep (192-thread version) ----
            const int idx = (b - 256) * 192 + tid;     // 0..12287
            const int l = idx / Dff;
            const int j = idx - l * Dff;
            float* o1 = W1P + (size_t)idx * WROW;
            float* o2 = W2P + (size_t)idx * WROW;
            #pragma unroll
            for (int d = 0; d < Dm; d++)
                o1[d] = fW1g[(size_t)l * Dm * Dff + (size_t)d * Dff + j];
            o1[18] = fb1g[l * Dff + j];
            o1[19] = 0.f;
            #pragma unroll
            for (int d = 0; d < Dm; d++)
                o2[d] = fW2g[((size_t)l * Dff + j) * Dm + d];
            o2[18] = 0.f;
            o2[19] = 0.f;
            if (idx < WROW) {             // zero pad row (prefetch guard)
                W1P[(size_t)6 * Dff * WROW + idx] = 0.f;
                W2P[(size_t)6 * Dff * WROW + idx] = 0.f;
            }
            return;
        }
        // ---- b == 320: tail precompute (Mw / PS1 / QS2) ----
        for (int m = tid; m < 602; m += 192) {
            int half = m / 301, rem = m - half * 301;
            int s = rem / 7, n = rem - 7 * s;
            float a = 0.f;
            for (int jj = 0; jj < Am; jj++)
                a += llW[s * Am + jj] * flW[(half * Am + jj) * Nb + n];
            M[m] = a;
        }
        if (tid < 14) {
            int half = tid / 7, n = tid - 7 * (tid / 7);
            float a = 0.f;
            for (int jj = 0; jj < Am; jj++)
                a += llb[jj] * flW[(half * Am + jj) * Nb + n];
            cc2[tid] = a;
        }
        __syncthreads();
        if (tid < 14) {
            int half = tid / 7, n = tid - 7 * (tid / 7);
            float s2 = 0.f;
            for (int s = 0; s < Sq; s++) s2 += M[half * 301 + s * 7 + n];
            SS[tid] = s2;
        }
        __syncthreads();
        for (int m = tid; m < 602; m += 192) Mw[m] = M[m];
        for (int m = tid; m < 896; m += 192) {
            int i = m / 7, n = m - 7 * i;
            PS1[m] = cc2[n] + ll2b[i] * SS[n];
            QS2[m] = cc2[7 + n] + ll2b[i] * SS[7 + n] + flb[n];
        }
        return;
    }

    // -------------------- main path: one batch per block --------------------
    const float scale = 0.40824829046386296f;  // 1/sqrt(6)
    const int h = tid >> 6;        // wave id = head 0..2
    const int q = tid & 63;        // lane = query row

    if (tid < Sq) ms[tid] = maskg[b * Sq + tid];

    float y[Dm];
    float qv6[6];
    if (q < Sq) {
        const size_t ro = (size_t)(b * Sq + q) * Dm;
        #pragma unroll
        for (int k = 0; k < 9; k++) {
            float2 t = *(const float2*)(Xi + ro + 2 * k);
            y[2 * k] = t.x; y[2 * k + 1] = t.y;
        }
        // LN1 (computed by all 3 waves redundantly -> identical bits)
        float mu = 0.f;
        #pragma unroll
        for (int d = 0; d < Dm; d++) mu += y[d];
        mu *= (1.f / Dm);
        float var = 0.f;
        #pragma unroll
        for (int d = 0; d < Dm; d++) { float t = y[d] - mu; var += t * t; }
        var *= (1.f / (Dm - 1));                 // ddof=1
        float isd = 1.f / (sqrtf(var) + EPSf);   // eps on sd
        float x2[Dm];
        #pragma unroll
        for (int d = 0; d < Dm; d++)
            x2[d] = ln1a[layer * Dm + d] * (y[d] - mu) * isd
                  + ln1b[layer * Dm + d];
        // q/k/v: ONLY this wave's head slice (d = h*6+dh), same chains
        const float* wqp = Wq + layer * Dm * Dm;
        const float* wkp = Wk + layer * Dm * Dm;
        const float* wvp = Wv + layer * Dm * Dm;
        #pragma unroll
        for (int dh = 0; dh < 6; dh++) {
            const int d = h * 6 + dh;
            float aq = bq[layer * Dm + d];
            float ak = bk[layer * Dm + d];
            float av = bv[layer * Dm + d];
            #pragma unroll
            for (int dd = 0; dd < Dm; dd++) {
                aq += x2[dd] * wqp[dd * Dm + d];
                ak += x2[dd] * wkp[dd * Dm + d];
                av += x2[dd] * wvp[dd * Dm + d];
            }
            qv6[dh] = aq;
            ks[q * 20 + d] = ak;
            vs[q * 20 + d] = av;
        }
    }
    __syncthreads();

    // phase 2: this wave's head attention (identical chain & j-order)
    if (q < Sq) {
        float sum = 0.f;
        float o6[6];
        #pragma unroll
        for (int d = 0; d < 6; d++) o6[d] = 0.f;
        const float q0 = qv6[0], q1 = qv6[1], q2 = qv6[2];
        const float q3 = qv6[3], q4 = qv6[4], q5 = qv6[5];
        for (int j = 0; j < Sq; j++) {
            const float* kr = ks + j * 20 + h * 6;   // 8B-aligned (h*6 even)
            const float2 k0 = *(const float2*)(kr);
            const float2 k1 = *(const float2*)(kr + 2);
            const float2 k2 = *(const float2*)(kr + 4);
            float t = q0 * k0.x + q1 * k0.y + q2 * k1.x +
                      q3 * k1.y + q4 * k2.x + q5 * k2.y;
            t *= scale;
            if (ms[j] == 0) t = -1e9f;
            float e = __expf(t);
            sum += e;
            const float* vr = vs + j * 20 + h * 6;
            const float2 v0 = *(const float2*)(vr);
            const float2 v1 = *(const float2*)(vr + 2);
            const float2 v2 = *(const float2*)(vr + 4);
            o6[0] += e * v0.x; o6[1] += e * v0.y; o6[2] += e * v1.x;
            o6[3] += e * v1.y; o6[4] += e * v2.x; o6[5] += e * v2.y;
        }
        float inv = 1.f / sum;
        #pragma unroll
        for (int d = 0; d < 6; d++) os[q * Dm + h * 6 + d] = o6[d] * inv;
    }
    __syncthreads();

    // phase 3: wave 0 -> o-proj + residual + next-x seed + LN2 (same chains)
    if (h == 0 && q < Sq) {
        const float* wo = Wo + layer * Dm * Dm;
        const float* orow = os + q * Dm;
        float yo[Dm];
        #pragma unroll 3
        for (int d = 0; d < Dm; d++) {
            float t = bo[layer * Dm + d];
            #pragma unroll
            for (int dd = 0; dd < Dm; dd++) t += orow[dd] * wo[dd * Dm + d];
            yo[d] = y[d] + t;
        }
        const size_t ro = (size_t)(b * Sq + q) * Dm;
        #pragma unroll
        for (int d = 0; d < Dm; d++)
            Xn[ro + d] = yo[d] + b2g[layer * Dm + d];  // seed: FFN atomics add
        float mu = 0.f;
        #pragma unroll
        for (int d = 0; d < Dm; d++) mu += yo[d];
        mu *= (1.f / Dm);
        float var = 0.f;
        #pragma unroll
        for (int d = 0; d < Dm; d++) { float t = yo[d] - mu; var += t * t; }
        var *= (1.f / (Dm - 1));
        float isd = 1.f / (sqrtf(var) + EPSf);
        #pragma unroll
        for (int d = 0; d < Dm; d++)
            x2g[ro + d] =
                ln2a[layer * Dm + d] * (yo[d] - mu) * isd + ln2b[layer * Dm + d];
    }
}

// ---------------------------------------------------------------------------
// k_ffn (R10): the unexplored cell of the {rows}x{prefetch} matrix:
// 2 ROWS PER THREAD **WITH** R4's 1-deep register prefetch.
//  - R4  (1 row,  prefetch): 42cyc compute x 3 waves = 126 < ~240cyc load
//    period -> ~50% SIMD idle (best so far, 511-era).
//  - R6  (2 rows, NO prefetch): latency fully exposed each iter -> worse.
//  - R10 (2 rows, prefetch): 84cyc x 3 waves = 252 >= period -> stalls
//    nearly vanish; weight-fetch instructions per launch halve.
// VGPR ~162 fits the (256,3) budget (168). Per-row math bit-identical to
// R4/R6 (same chains, j-order, wave-ascending reduce, atomics) -> absmax
// must stay exactly 0.001953125. Grid 688 = 86 rg(128 rows) x 8 q-chunks.
// ---------------------------------------------------------------------------
__global__ __launch_bounds__(256, 3) void k_ffn(
    int layer, const float* __restrict__ x2g,
    const float* __restrict__ W1P, const float* __restrict__ W2P,
    float* __restrict__ Xn)
{
    __shared__ float Ls[4 * 128 * Dm];   // 36 KiB (final reduce only)

    const int tid  = threadIdx.x;
    const int lane = tid & 63;
    const int wv   = __builtin_amdgcn_readfirstlane(tid >> 6);
    const int rg   = blockIdx.x >> 3;     // 0..85 (128-row groups)
    const int q    = blockIdx.x & 7;      // 0..7
    const int row0 = rg * 128 + lane;
    const int row1 = row0 + 64;
    const int j0   = q * 256 + wv * 64;

    const v4f* w1p = (const v4f*)(W1P + ((size_t)layer * Dff + j0) * WROW);
    const v4f* w2p = (const v4f*)(W2P + ((size_t)layer * Dff + j0) * WROW);

    v2f xp0[9], xp1[9];
    #pragma unroll
    for (int k = 0; k < 9; k++) {
        xp0[k] = *(const v2f*)(x2g + (size_t)row0 * Dm + 2 * k);
        xp1[k] = *(const v2f*)(x2g + (size_t)row1 * Dm + 2 * k);
    }

    v2f acc0[9], acc1[9];
    #pragma unroll
    for (int k = 0; k < 9; k++) {
        acc0[k] = (v2f){0.f, 0.f};
        acc1[k] = (v2f){0.f, 0.f};
    }

    v4f a0 = w1p[0], a1 = w1p[1], a2 = w1p[2], a3 = w1p[3], a4 = w1p[4];
    v4f c0 = w2p[0], c1 = w2p[1], c2 = w2p[2], c3 = w2p[3], c4 = w2p[4];

    for (int jj = 0; jj < 64; jj++) {
        const v4f* n1 = w1p + (jj + 1) * 5;        // pad row guards j=2048
        const v4f* n2 = w2p + (jj + 1) * 5;
        const v4f na0 = n1[0], na1 = n1[1], na2 = n1[2], na3 = n1[3], na4 = n1[4];
        const v4f nc0 = n2[0], nc1 = n2[1], nc2 = n2[2], nc3 = n2[3], nc4 = n2[4];

        // h row0: two 9-term packed chains (even d in .x, odd d in .y)
        v2f h2a = xp0[0] * a0.lo;
        h2a = __builtin_elementwise_fma(xp0[1], a0.hi, h2a);
        h2a = __builtin_elementwise_fma(xp0[2], a1.lo, h2a);
        h2a = __builtin_elementwise_fma(xp0[3], a1.hi, h2a);
        h2a = __builtin_elementwise_fma(xp0[4], a2.lo, h2a);
        h2a = __builtin_elementwise_fma(xp0[5], a2.hi, h2a);
        h2a = __builtin_elementwise_fma(xp0[6], a3.lo, h2a);
        h2a = __builtin_elementwise_fma(xp0[7], a3.hi, h2a);
        h2a = __builtin_elementwise_fma(xp0[8], a4.lo, h2a);
        float ha = a4.z + h2a.x + h2a.y;           // b1 in slot 18
        ha = fmaxf(ha, 0.f);
        const v2f hha = {ha, ha};

        // h row1 (same weight registers)
        v2f h2b = xp1[0] * a0.lo;
        h2b = __builtin_elementwise_fma(xp1[1], a0.hi, h2b);
        h2b = __builtin_elementwise_fma(xp1[2], a1.lo, h2b);
        h2b = __builtin_elementwise_fma(xp1[3], a1.hi, h2b);
        h2b = __builtin_elementwise_fma(xp1[4], a2.lo, h2b);
        h2b = __builtin_elementwise_fma(xp1[5], a2.hi, h2b);
        h2b = __builtin_elementwise_fma(xp1[6], a3.lo, h2b);
        h2b = __builtin_elementwise_fma(xp1[7], a3.hi, h2b);
        h2b = __builtin_elementwise_fma(xp1[8], a4.lo, h2b);
        float hb = a4.z + h2b.x + h2b.y;
        hb = fmaxf(hb, 0.f);
        const v2f hhb = {hb, hb};

        acc0[0] = __builtin_elementwise_fma(hha, c0.lo, acc0[0]);
        acc0[1] = __builtin_elementwise_fma(hha, c0.hi, acc0[1]);
        acc0[2] = __builtin_elementwise_fma(hha, c1.lo, acc0[2]);
        acc0[3] = __builtin_elementwise_fma(hha, c1.hi, acc0[3]);
        acc0[4] = __builtin_elementwise_fma(hha, c2.lo, acc0[4]);
        acc0[5] = __builtin_elementwise_fma(hha, c2.hi, acc0[5]);
        acc0[6] = __builtin_elementwise_fma(hha, c3.lo, acc0[6]);
        acc0[7] = __builtin_elementwise_fma(hha, c3.hi, acc0[7]);
        acc0[8] = __builtin_elementwise_fma(hha, c4.lo, acc0[8]);

        acc1[0] = __builtin_elementwise_fma(hhb, c0.lo, acc1[0]);
        acc1[1] = __builtin_elementwise_fma(hhb, c0.hi, acc1[1]);
        acc1[2] = __builtin_elementwise_fma(hhb, c1.lo, acc1[2]);
        acc1[3] = __builtin_elementwise_fma(hhb, c1.hi, acc1[3]);
        acc1[4] = __builtin_elementwise_fma(hhb, c2.lo, acc1[4]);
        acc1[5] = __builtin_elementwise_fma(hhb, c2.hi, acc1[5]);
        acc1[6] = __builtin_elementwise_fma(hhb, c3.lo, acc1[6]);
        acc1[7] = __builtin_elementwise_fma(hhb, c3.hi, acc1[7]);
        acc1[8] = __builtin_elementwise_fma(hhb, c4.lo, acc1[8]);

        a0 = na0; a1 = na1; a2 = na2; a3 = na3; a4 = na4;
        c0 = nc0; c1 = nc1; c2 = nc2; c3 = nc3; c4 = nc4;
    }

    // ---- cross-wave reduce (layout [wave][row_in_128][18], as R6) ----
    #pragma unroll
    for (int k = 0; k < 9; k++) {
        Ls[(wv * 128 + lane) * Dm + 2 * k]          = acc0[k].x;
        Ls[(wv * 128 + lane) * Dm + 2 * k + 1]      = acc0[k].y;
        Ls[(wv * 128 + lane + 64) * Dm + 2 * k]     = acc1[k].x;
        Ls[(wv * 128 + lane + 64) * Dm + 2 * k + 1] = acc1[k].y;
    }
    __syncthreads();
    for (int e = tid; e < 2304; e += 256) {
        float s = Ls[e] + Ls[2304 + e] + Ls[4608 + e] + Ls[6912 + e];
        unsafeAtomicAdd(&Xn[(size_t)rg * 2304 + e], s);
    }
}

// ---------------------------------------------------------------------------
// k_out: (i-chunk, batch) blocks; float4 stores of the 117 MB output.
// (UNCHANGED)
// ---------------------------------------------------------------------------
__global__ __launch_bounds__(256) void k_out(
    const float* __restrict__ xg,
    const float* __restrict__ ll2W,
    const float* __restrict__ Mw, const float* __restrict__ PS1,
    const float* __restrict__ QS2, float* __restrict__ out)
{
    __shared__ float xb[Sq * Dm];
    __shared__ float M[602];
    __shared__ float T[2][Dm][Nb];
    __shared__ float Pc[32 * Nb];
    __shared__ float QBs[Am * Nb];

    const int b = blockIdx.y, chunk = blockIdx.x, tid = threadIdx.x;

    for (int e = tid; e < Sq * Dm; e += 256)
        xb[e] = xg[(size_t)b * (Sq * Dm) + e];
    for (int m = tid; m < 602; m += 256) M[m] = Mw[m];
    __syncthreads();

    for (int m = tid; m < 252; m += 256) {
        int half = m / 126, rem = m - half * 126;
        int d = rem / 7, n = rem - 7 * d;
        float a = 0.f;
        for (int s = 0; s < Sq; s++)
            a += xb[s * Dm + d] * M[half * 301 + s * 7 + n];
        T[half][d][n] = a;
    }
    __syncthreads();

    for (int m = tid; m < 224; m += 256) {
        int il = m / 7, n = m - 7 * il;
        int i = chunk * 32 + il;
        float a = PS1[i * 7 + n];
        #pragma unroll
        for (int d = 0; d < Dm; d++) a += T[0][d][n] * ll2W[d * Am + i];
        Pc[m] = a;
    }
    for (int e = tid; e < 896; e += 256) {
        int jj = e / 7, n = e - 7 * jj;
        float a = QS2[e];
        #pragma unroll
        for (int d = 0; d < Dm; d++) a += T[1][d][n] * ll2W[d * Am + jj];
        QBs[e] = a;
    }
    __syncthreads();

    if (tid < 224) {
        const int e = 4 * tid;
        const float q0 = QBs[e], q1 = QBs[e + 1], q2 = QBs[e + 2], q3 = QBs[e + 3];
        const int n0 = e % 7, n1 = (e + 1) % 7, n2 = (e + 2) % 7, n3 = (e + 3) % 7;
        const size_t base = (size_t)b * (Am * Am * Nb)
                          + (size_t)chunk * 32 * 896 + e;
        for (int il = 0; il < 32; il++) {
            const float* pc = Pc + il * 7;
            float4 v;
            v.x = pc[n0] + q0; v.y = pc[n1] + q1;
            v.z = pc[n2] + q2; v.w = pc[n3] + q3;
            *(float4*)(out + base + (size_t)il * 896) = v;
        }
    }
}

} // namespace

// ---------------------------------------------------------------------------
extern "C" void kernel_launch(void* const* d_in, const int* in_sizes, int n_in,
                              void* d_out, int out_size, void* d_ws, size_t ws_size,
                              hipStream_t stream)
{
    (void)in_sizes; (void)n_in; (void)out_size; (void)ws_size;

    const float* src  = (const float*)d_in[0];
    const int*   mask = (const int*)  d_in[1];
    const float* Wq   = (const float*)d_in[3];
    const float* bq   = (const float*)d_in[4];
    const float* Wk   = (const float*)d_in[5];
    const float* bk   = (const float*)d_in[6];
    const float* Wv   = (const float*)d_in[7];
    const float* bv   = (const float*)d_in[8];
    const float* Wo   = (const float*)d_in[9];
    const float* bo   = (const float*)d_in[10];
    const float* ln1a = (const float*)d_in[11];
    const float* ln1b = (const float*)d_in[12];
    const float* ln2a = (const float*)d_in[13];
    const float* ln2b = (const float*)d_in[14];
    const float* fW1  = (const float*)d_in[15];
    const float* fb1  = (const float*)d_in[16];
    const float* fW2  = (const float*)d_in[17];
    const float* fb2  = (const float*)d_in[18];
    const float* ll2W = (const float*)d_in[19];
    const float* ll2b = (const float*)d_in[20];
    const float* llW  = (const float*)d_in[21];
    const float* llb  = (const float*)d_in[22];
    const float* flW  = (const float*)d_in[23];
    const float* flb  = (const float*)d_in[24];
    float* out = (float*)d_out;

    const size_t WPSZ = (size_t)6 * Dff * WROW + WROW;   // 245780

    float* ws  = (float*)d_ws;
    float* xA  = ws;
    float* xB  = ws + 1 * (size_t)RSZ;
    float* x2g = ws + 2 * (size_t)RSZ;
    float* W1P = ws + 3 * (size_t)RSZ;
    float* W2P = W1P + WPSZ;
    float* Mw  = W2P + WPSZ;                  // 602 (pad 604)
    float* PS1 = Mw + 604;
    float* QS2 = PS1 + 896;                   // total ~4.4 MB

    for (int i = 0; i < 6; i++) {
        const float* Xi = (i == 0) ? src : ((i % 2 == 1) ? xB : xA);
        float*       Xn = (i % 2 == 0) ? xB : xA;
        const int nblk = (i == 0) ? 321 : 256;   // layer 0 carries prep blocks
        k_attn<<<nblk, 192, 0, stream>>>(i, Xi, Xn, x2g, mask,
                                         Wq, bq, Wk, bk, Wv, bv,
                                         ln1a, ln1b, Wo, bo, ln2a, ln2b, fb2,
                                         fW1, fb1, fW2, W1P, W2P,
                                         llW, llb, flW, flb, ll2b,
                                         Mw, PS1, QS2);
        k_ffn<<<688, 256, 0, stream>>>(i, x2g, W1P, W2P, Xn);
    }
    k_out<<<dim3(4, 256), 256, 0, stream>>>(xA, ll2W, Mw, PS1, QS2, out);
}

// Round 12
// 484.244 us; speedup vs baseline: 1.1286x; 1.0230x over previous
//
#include <hip/hip_runtime.h>
#include <math.h>

namespace {

constexpr int Sq = 43;
constexpr int Dm = 18;
constexpr int Dff = 2048;
constexpr int Am = 128;
constexpr int Nb = 7;
constexpr int NR = 11008;          // B*SEQ rows
constexpr int RSZ = NR * Dm;       // 198144 floats
constexpr int WROW = 20;           // padded weight row (18 w + b1 + pad)
constexpr float EPSf = 1e-6f;

typedef float v2f __attribute__((ext_vector_type(2)));
typedef float v4f __attribute__((ext_vector_type(4)));

// ---------------------------------------------------------------------------
// k_attn (R7, verbatim): head-parallel. 192 threads = 3 waves; wave h = head h.
//   blocks 0..255  : batch b.
//   layer-0 extras : 256..319 FFN weight prep (padded fp32 rows); 320 tail.
// ---------------------------------------------------------------------------
__global__ __launch_bounds__(192) void k_attn(
    int layer,
    const float* __restrict__ Xi, float* __restrict__ Xn,
    float* __restrict__ x2g,
    const int* __restrict__ maskg,
    const float* __restrict__ Wq, const float* __restrict__ bq,
    const float* __restrict__ Wk, const float* __restrict__ bk,
    const float* __restrict__ Wv, const float* __restrict__ bv,
    const float* __restrict__ ln1a, const float* __restrict__ ln1b,
    const float* __restrict__ Wo, const float* __restrict__ bo,
    const float* __restrict__ ln2a, const float* __restrict__ ln2b,
    const float* __restrict__ b2g,
    const float* __restrict__ fW1g, const float* __restrict__ fb1g,
    const float* __restrict__ fW2g,
    float* __restrict__ W1P, float* __restrict__ W2P,
    const float* __restrict__ llW, const float* __restrict__ llb,
    const float* __restrict__ flW, const float* __restrict__ flb,
    const float* __restrict__ ll2b,
    float* __restrict__ Mw, float* __restrict__ PS1, float* __restrict__ QS2)
{
    __shared__ __align__(16) float ks[Sq * 20];
    __shared__ __align__(16) float vs[Sq * 20];
    __shared__ float os[Sq * Dm];
    __shared__ int ms[Sq];
    __shared__ float M[602];
    __shared__ float cc2[14];
    __shared__ float SS[14];

    const int tid = threadIdx.x;
    const int b = blockIdx.x;

    if (b >= 256) {                       // layer-0 auxiliary blocks only
        if (b < 320) {
            // ---- FFN weight prep (192-thread version) ----
            const int idx = (b - 256) * 192 + tid;     // 0..12287
            const int l = idx / Dff;
            const int j = idx - l * Dff;
            float* o1 = W1P + (size_t)idx * WROW;
            float* o2 = W2P + (size_t)idx * WROW;
            #pragma unroll
            for (int d = 0; d < Dm; d++)
                o1[d] = fW1g[(size_t)l * Dm * Dff + (size_t)d * Dff + j];
            o1[18] = fb1g[l * Dff + j];
            o1[19] = 0.f;
            #pragma unroll
            for (int d = 0; d < Dm; d++)
                o2[d] = fW2g[((size_t)l * Dff + j) * Dm + d];
            o2[18] = 0.f;
            o2[19] = 0.f;
            if (idx < WROW) {             // zero pad row (safety guard)
                W1P[(size_t)6 * Dff * WROW + idx] = 0.f;
                W2P[(size_t)6 * Dff * WROW + idx] = 0.f;
            }
            return;
        }
        // ---- b == 320: tail precompute (Mw / PS1 / QS2) ----
        for (int m = tid; m < 602; m += 192) {
            int half = m / 301, rem = m - half * 301;
            int s = rem / 7, n = rem - 7 * s;
            float a = 0.f;
            for (int jj = 0; jj < Am; jj++)
                a += llW[s * Am + jj] * flW[(half * Am + jj) * Nb + n];
            M[m] = a;
        }
        if (tid < 14) {
            int half = tid / 7, n = tid - 7 * (tid / 7);
            float a = 0.f;
            for (int jj = 0; jj < Am; jj++)
                a += llb[jj] * flW[(half * Am + jj) * Nb + n];
            cc2[tid] = a;
        }
        __syncthreads();
        if (tid < 14) {
            int half = tid / 7, n = tid - 7 * (tid / 7);
            float s2 = 0.f;
            for (int s = 0; s < Sq; s++) s2 += M[half * 301 + s * 7 + n];
            SS[tid] = s2;
        }
        __syncthreads();
        for (int m = tid; m < 602; m += 192) Mw[m] = M[m];
        for (int m = tid; m < 896; m += 192) {
            int i = m / 7, n = m - 7 * i;
            PS1[m] = cc2[n] + ll2b[i] * SS[n];
            QS2[m] = cc2[7 + n] + ll2b[i] * SS[7 + n] + flb[n];
        }
        return;
    }

    // -------------------- main path: one batch per block --------------------
    const float scale = 0.40824829046386296f;  // 1/sqrt(6)
    const int h = tid >> 6;        // wave id = head 0..2
    const int q = tid & 63;        // lane = query row

    if (tid < Sq) ms[tid] = maskg[b * Sq + tid];

    float y[Dm];
    float qv6[6];
    if (q < Sq) {
        const size_t ro = (size_t)(b * Sq + q) * Dm;
        #pragma unroll
        for (int k = 0; k < 9; k++) {
            float2 t = *(const float2*)(Xi + ro + 2 * k);
            y[2 * k] = t.x; y[2 * k + 1] = t.y;
        }
        // LN1 (computed by all 3 waves redundantly -> identical bits)
        float mu = 0.f;
        #pragma unroll
        for (int d = 0; d < Dm; d++) mu += y[d];
        mu *= (1.f / Dm);
        float var = 0.f;
        #pragma unroll
        for (int d = 0; d < Dm; d++) { float t = y[d] - mu; var += t * t; }
        var *= (1.f / (Dm - 1));                 // ddof=1
        float isd = 1.f / (sqrtf(var) + EPSf);   // eps on sd
        float x2[Dm];
        #pragma unroll
        for (int d = 0; d < Dm; d++)
            x2[d] = ln1a[layer * Dm + d] * (y[d] - mu) * isd
                  + ln1b[layer * Dm + d];
        // q/k/v: ONLY this wave's head slice (d = h*6+dh), same chains
        const float* wqp = Wq + layer * Dm * Dm;
        const float* wkp = Wk + layer * Dm * Dm;
        const float* wvp = Wv + layer * Dm * Dm;
        #pragma unroll
        for (int dh = 0; dh < 6; dh++) {
            const int d = h * 6 + dh;
            float aq = bq[layer * Dm + d];
            float ak = bk[layer * Dm + d];
            float av = bv[layer * Dm + d];
            #pragma unroll
            for (int dd = 0; dd < Dm; dd++) {
                aq += x2[dd] * wqp[dd * Dm + d];
                ak += x2[dd] * wkp[dd * Dm + d];
                av += x2[dd] * wvp[dd * Dm + d];
            }
            qv6[dh] = aq;
            ks[q * 20 + d] = ak;
            vs[q * 20 + d] = av;
        }
    }
    __syncthreads();

    // phase 2: this wave's head attention (identical chain & j-order)
    if (q < Sq) {
        float sum = 0.f;
        float o6[6];
        #pragma unroll
        for (int d = 0; d < 6; d++) o6[d] = 0.f;
        const float q0 = qv6[0], q1 = qv6[1], q2 = qv6[2];
        const float q3 = qv6[3], q4 = qv6[4], q5 = qv6[5];
        for (int j = 0; j < Sq; j++) {
            const float* kr = ks + j * 20 + h * 6;   // 8B-aligned (h*6 even)
            const float2 k0 = *(const float2*)(kr);
            const float2 k1 = *(const float2*)(kr + 2);
            const float2 k2 = *(const float2*)(kr + 4);
            float t = q0 * k0.x + q1 * k0.y + q2 * k1.x +
                      q3 * k1.y + q4 * k2.x + q5 * k2.y;
            t *= scale;
            if (ms[j] == 0) t = -1e9f;
            float e = __expf(t);
            sum += e;
            const float* vr = vs + j * 20 + h * 6;
            const float2 v0 = *(const float2*)(vr);
            const float2 v1 = *(const float2*)(vr + 2);
            const float2 v2 = *(const float2*)(vr + 4);
            o6[0] += e * v0.x; o6[1] += e * v0.y; o6[2] += e * v1.x;
            o6[3] += e * v1.y; o6[4] += e * v2.x; o6[5] += e * v2.y;
        }
        float inv = 1.f / sum;
        #pragma unroll
        for (int d = 0; d < 6; d++) os[q * Dm + h * 6 + d] = o6[d] * inv;
    }
    __syncthreads();

    // phase 3: wave 0 -> o-proj + residual + next-x seed + LN2 (same chains)
    if (h == 0 && q < Sq) {
        const float* wo = Wo + layer * Dm * Dm;
        const float* orow = os + q * Dm;
        float yo[Dm];
        #pragma unroll 3
        for (int d = 0; d < Dm; d++) {
            float t = bo[layer * Dm + d];
            #pragma unroll
            for (int dd = 0; dd < Dm; dd++) t += orow[dd] * wo[dd * Dm + d];
            yo[d] = y[d] + t;
        }
        const size_t ro = (size_t)(b * Sq + q) * Dm;
        #pragma unroll
        for (int d = 0; d < Dm; d++)
            Xn[ro + d] = yo[d] + b2g[layer * Dm + d];  // seed: FFN atomics add
        float mu = 0.f;
        #pragma unroll
        for (int d = 0; d < Dm; d++) mu += yo[d];
        mu *= (1.f / Dm);
        float var = 0.f;
        #pragma unroll
        for (int d = 0; d < Dm; d++) { float t = yo[d] - mu; var += t * t; }
        var *= (1.f / (Dm - 1));
        float isd = 1.f / (sqrtf(var) + EPSf);
        #pragma unroll
        for (int d = 0; d < Dm; d++)
            x2g[ro + d] =
                ln2a[layer * Dm + d] * (yo[d] - mu) * isd + ln2b[layer * Dm + d];
    }
}

// ---------------------------------------------------------------------------
// k_ffn (R11 resubmit): the untested OCCUPANCY cell. R4's inner math
// (1 row/thread, packed fp32 via compiler ISel) with the 1-deep register
// prefetch REMOVED: prefetch cost ~40 VGPRs, pinning every prior variant at
// 3 waves/SIMD. Without it (~90 VGPR), __launch_bounds__(256,4) gives
// 4 blocks/CU = 16 waves/CU = 4 waves/SIMD -> +33% TLP latency cover.
// ILP(prefetch) and TLP(occupancy) are mutually exclusive through the VGPR
// budget; R4 tested ILP@3, this tests TLP@4. Math bit-identical to R4
// (same pk chains, j-order, wave-ascending reduce, atomics) -> absmax must
// stay 0.001953125. Grid 1376 = 172 rg x 8 q-chunks, as R4.
// ---------------------------------------------------------------------------
__global__ __launch_bounds__(256, 4) void k_ffn(
    int layer, const float* __restrict__ x2g,
    const float* __restrict__ W1P, const float* __restrict__ W2P,
    float* __restrict__ Xn)
{
    __shared__ float Ls[4 * 64 * Dm];   // 18 KiB (final reduce only)

    const int tid  = threadIdx.x;
    const int lane = tid & 63;
    const int wv   = __builtin_amdgcn_readfirstlane(tid >> 6);
    const int rg   = blockIdx.x >> 3;     // 0..171
    const int q    = blockIdx.x & 7;      // 0..7
    const int row  = rg * 64 + lane;
    const int j0   = q * 256 + wv * 64;

    const v4f* w1p = (const v4f*)(W1P + ((size_t)layer * Dff + j0) * WROW);
    const v4f* w2p = (const v4f*)(W2P + ((size_t)layer * Dff + j0) * WROW);

    v2f xp[9];
    #pragma unroll
    for (int k = 0; k < 9; k++)
        xp[k] = *(const v2f*)(x2g + (size_t)row * Dm + 2 * k);

    v2f acc2[9];
    #pragma unroll
    for (int k = 0; k < 9; k++) acc2[k] = (v2f){0.f, 0.f};

    #pragma unroll 2
    for (int jj = 0; jj < 64; jj++) {
        const v4f a0 = w1p[jj * 5 + 0], a1 = w1p[jj * 5 + 1],
                  a2 = w1p[jj * 5 + 2], a3 = w1p[jj * 5 + 3],
                  a4 = w1p[jj * 5 + 4];
        const v4f c0 = w2p[jj * 5 + 0], c1 = w2p[jj * 5 + 1],
                  c2 = w2p[jj * 5 + 2], c3 = w2p[jj * 5 + 3],
                  c4 = w2p[jj * 5 + 4];

        // h: two 9-term packed chains (even d in .x, odd d in .y)
        v2f h2 = xp[0] * a0.lo;
        h2 = __builtin_elementwise_fma(xp[1], a0.hi, h2);
        h2 = __builtin_elementwise_fma(xp[2], a1.lo, h2);
        h2 = __builtin_elementwise_fma(xp[3], a1.hi, h2);
        h2 = __builtin_elementwise_fma(xp[4], a2.lo, h2);
        h2 = __builtin_elementwise_fma(xp[5], a2.hi, h2);
        h2 = __builtin_elementwise_fma(xp[6], a3.lo, h2);
        h2 = __builtin_elementwise_fma(xp[7], a3.hi, h2);
        h2 = __builtin_elementwise_fma(xp[8], a4.lo, h2);
        float h = a4.z + h2.x + h2.y;              // b1 in slot 18
        h = fmaxf(h, 0.f);
        const v2f hh = {h, h};

        acc2[0] = __builtin_elementwise_fma(hh, c0.lo, acc2[0]);
        acc2[1] = __builtin_elementwise_fma(hh, c0.hi, acc2[1]);
        acc2[2] = __builtin_elementwise_fma(hh, c1.lo, acc2[2]);
        acc2[3] = __builtin_elementwise_fma(hh, c1.hi, acc2[3]);
        acc2[4] = __builtin_elementwise_fma(hh, c2.lo, acc2[4]);
        acc2[5] = __builtin_elementwise_fma(hh, c2.hi, acc2[5]);
        acc2[6] = __builtin_elementwise_fma(hh, c3.lo, acc2[6]);
        acc2[7] = __builtin_elementwise_fma(hh, c3.hi, acc2[7]);
        acc2[8] = __builtin_elementwise_fma(hh, c4.lo, acc2[8]);
    }

    #pragma unroll
    for (int k = 0; k < 9; k++) {
        Ls[(wv * 64 + lane) * Dm + 2 * k]     = acc2[k].x;
        Ls[(wv * 64 + lane) * Dm + 2 * k + 1] = acc2[k].y;
    }
    __syncthreads();
    for (int e = tid; e < 1152; e += 256) {
        float s = Ls[e] + Ls[1152 + e] + Ls[2304 + e] + Ls[3456 + e];
        unsafeAtomicAdd(&Xn[(size_t)rg * 1152 + e], s);
    }
}

// ---------------------------------------------------------------------------
// k_out (R11 resubmit): chunk split 4 -> 8 (grid 8x256, 16 i per block) for
// 2x store parallelism in the pure-store phase (117 MB, 18.6 us write
// floor). The T/QBs precompute is recomputed per chunk (cheap); per-element
// output math and values bit-identical to before.
// ---------------------------------------------------------------------------
__global__ __launch_bounds__(256) void k_out(
    const float* __restrict__ xg,
    const float* __restrict__ ll2W,
    const float* __restrict__ Mw, const float* __restrict__ PS1,
    const float* __restrict__ QS2, float* __restrict__ out)
{
    __shared__ float xb[Sq * Dm];
    __shared__ float M[602];
    __shared__ float T[2][Dm][Nb];
    __shared__ float Pc[16 * Nb];
    __shared__ float QBs[Am * Nb];

    const int b = blockIdx.y, chunk = blockIdx.x, tid = threadIdx.x;

    for (int e = tid; e < Sq * Dm; e += 256)
        xb[e] = xg[(size_t)b * (Sq * Dm) + e];
    for (int m = tid; m < 602; m += 256) M[m] = Mw[m];
    __syncthreads();

    for (int m = tid; m < 252; m += 256) {
        int half = m / 126, rem = m - half * 126;
        int d = rem / 7, n = rem - 7 * d;
        float a = 0.f;
        for (int s = 0; s < Sq; s++)
            a += xb[s * Dm + d] * M[half * 301 + s * 7 + n];
        T[half][d][n] = a;
    }
    __syncthreads();

    for (int m = tid; m < 112; m += 256) {
        int il = m / 7, n = m - 7 * il;
        int i = chunk * 16 + il;
        float a = PS1[i * 7 + n];
        #pragma unroll
        for (int d = 0; d < Dm; d++) a += T[0][d][n] * ll2W[d * Am + i];
        Pc[m] = a;
    }
    for (int e = tid; e < 896; e += 256) {
        int jj = e / 7, n = e - 7 * jj;
        float a = QS2[e];
        #pragma unroll
        for (int d = 0; d < Dm; d++) a += T[1][d][n] * ll2W[d * Am + jj];
        QBs[e] = a;
    }
    __syncthreads();

    if (tid < 224) {
        const int e = 4 * tid;
        const float q0 = QBs[e], q1 = QBs[e + 1], q2 = QBs[e + 2], q3 = QBs[e + 3];
        const int n0 = e % 7, n1 = (e + 1) % 7, n2 = (e + 2) % 7, n3 = (e + 3) % 7;
        const size_t base = (size_t)b * (Am * Am * Nb)
                          + (size_t)chunk * 16 * 896 + e;
        for (int il = 0; il < 16; il++) {
            const float* pc = Pc + il * 7;
            float4 v;
            v.x = pc[n0] + q0; v.y = pc[n1] + q1;
            v.z = pc[n2] + q2; v.w = pc[n3] + q3;
            *(float4*)(out + base + (size_t)il * 896) = v;
        }
    }
}

} // namespace

// ---------------------------------------------------------------------------
extern "C" void kernel_launch(void* const* d_in, const int* in_sizes, int n_in,
                              void* d_out, int out_size, void* d_ws, size_t ws_size,
                              hipStream_t stream)
{
    (void)in_sizes; (void)n_in; (void)out_size; (void)ws_size;

    const float* src  = (const float*)d_in[0];
    const int*   mask = (const int*)  d_in[1];
    const float* Wq   = (const float*)d_in[3];
    const float* bq   = (const float*)d_in[4];
    const float* Wk   = (const float*)d_in[5];
    const float* bk   = (const float*)d_in[6];
    const float* Wv   = (const float*)d_in[7];
    const float* bv   = (const float*)d_in[8];
    const float* Wo   = (const float*)d_in[9];
    const float* bo   = (const float*)d_in[10];
    const float* ln1a = (const float*)d_in[11];
    const float* ln1b = (const float*)d_in[12];
    const float* ln2a = (const float*)d_in[13];
    const float* ln2b = (const float*)d_in[14];
    const float* fW1  = (const float*)d_in[15];
    const float* fb1  = (const float*)d_in[16];
    const float* fW2  = (const float*)d_in[17];
    const float* fb2  = (const float*)d_in[18];
    const float* ll2W = (const float*)d_in[19];
    const float* ll2b = (const float*)d_in[20];
    const float* llW  = (const float*)d_in[21];
    const float* llb  = (const float*)d_in[22];
    const float* flW  = (const float*)d_in[23];
    const float* flb  = (const float*)d_in[24];
    float* out = (float*)d_out;

    const size_t WPSZ = (size_t)6 * Dff * WROW + WROW;   // 245780

    float* ws  = (float*)d_ws;
    float* xA  = ws;
    float* xB  = ws + 1 * (size_t)RSZ;
    float* x2g = ws + 2 * (size_t)RSZ;
    float* W1P = ws + 3 * (size_t)RSZ;
    float* W2P = W1P + WPSZ;
    float* Mw  = W2P + WPSZ;                  // 602 (pad 604)
    float* PS1 = Mw + 604;
    float* QS2 = PS1 + 896;                   // total ~4.4 MB

    for (int i = 0; i < 6; i++) {
        const float* Xi = (i == 0) ? src : ((i % 2 == 1) ? xB : xA);
        float*       Xn = (i % 2 == 0) ? xB : xA;
        const int nblk = (i == 0) ? 321 : 256;   // layer 0 carries prep blocks
        k_attn<<<nblk, 192, 0, stream>>>(i, Xi, Xn, x2g, mask,
                                         Wq, bq, Wk, bk, Wv, bv,
                                         ln1a, ln1b, Wo, bo, ln2a, ln2b, fb2,
                                         fW1, fb1, fW2, W1P, W2P,
                                         llW, llb, flW, flb, ll2b,
                                         Mw, PS1, QS2);
        k_ffn<<<1376, 256, 0, stream>>>(i, x2g, W1P, W2P, Xn);
    }
    k_out<<<dim3(8, 256), 256, 0, stream>>>(xA, ll2W, Mw, PS1, QS2, out);
}